// Round 2
// baseline (54750.055 us; speedup 1.0000x reference)
//
#include <hip/hip_runtime.h>
#include <math.h>

// DARTS recurrent cell on MI355X — MFMA fp16 3-limb split-precision GEMMs.
// x = l0 + l1/2048 + l2/2048^2 (limbs scaled into fp16 normal range).
// acc = A*W computed as 6 MFMAs into 3 accumulators (scale 1, 1/2K, 1/2K^2).
// Per-op error ~ fp32 (33 bits), needed: 256-step recurrence amplifies ~1e4x.

typedef __attribute__((ext_vector_type(8))) _Float16 half8;
typedef __attribute__((ext_vector_type(4))) float f32x4;
typedef __attribute__((ext_vector_type(8))) unsigned short us8;

#define NH 1024
#define WSZ (1024 * 2048)

#define ACT_SIGMOID 0
#define ACT_RELU    1
#define ACT_IDENT   2
#define ACT_TANH    3

#define SPLIT_SCALE 2048.f
#define INV_SCALE   (1.f / 2048.f)

// Wf fragment layout (ushort units): per matrix, frag f = ((cg*KS + ks)*3 + limb),
// element offset = f*512 + lane*8 + j.  cg: 16-col group (0..127), ks: 32-k step.
#define WF_W0_US   12582912ull          // 128*64*3*512
#define WF_WS_US    6291456ull          // 128*32*3*512
#define WF_TOTAL_US (WF_W0_US + 8ull * WF_WS_US)   // 62,914,560 ushorts = 125.8 MB

__device__ __forceinline__ float sigf(float x) { return 1.f / (1.f + expf(-x)); }
__device__ __forceinline__ float actf(int a, float x) {
    if (a == ACT_SIGMOID) return sigf(x);
    if (a == ACT_RELU)    return x > 0.f ? x : 0.f;
    if (a == ACT_TANH)    return tanhf(x);
    return x;
}

__device__ __forceinline__ void limbs3(float x, unsigned short& u0,
                                       unsigned short& u1, unsigned short& u2) {
    _Float16 a0 = (_Float16)x;
    float r1 = (x - (float)a0) * SPLIT_SCALE;
    _Float16 a1 = (_Float16)r1;
    float r2 = (r1 - (float)a1) * SPLIT_SCALE;
    _Float16 a2 = (_Float16)r2;
    u0 = __builtin_bit_cast(unsigned short, a0);
    u1 = __builtin_bit_cast(unsigned short, a1);
    u2 = __builtin_bit_cast(unsigned short, a2);
}

// ---------------- weight pre-swizzle into MFMA fragment order -----------------
struct PreDesc { const float* W0; const float* Ws; unsigned short* Wf; };

__global__ __launch_bounds__(256) void preconv_kernel(PreDesc d) {
    int gid  = blockIdx.x * 4 + (threadIdx.x >> 6);
    int lane = threadIdx.x & 63;
    const float* W; size_t wfbase; int KS, cg, ks;
    if (gid < 8192) {               // W0: 128 cg * 64 ks
        W = d.W0; wfbase = 0; KS = 64; cg = gid >> 6; ks = gid & 63;
    } else {
        int g2 = gid - 8192;        // Ws[m]: 128 cg * 32 ks each
        int m  = g2 >> 12;
        int wi = g2 & 4095;
        W = d.Ws + (size_t)m * WSZ;
        wfbase = WF_W0_US + (size_t)m * WF_WS_US;
        KS = 32; cg = wi >> 5; ks = wi & 31;
    }
    int c  = cg * 16 + (lane & 15);
    int kb = ks * 32 + (lane >> 4) * 8;
    us8 h0, h1, h2;
    #pragma unroll
    for (int j = 0; j < 8; ++j) {
        float w = W[(size_t)(kb + j) * 2048 + c];
        unsigned short a, b, cc;
        limbs3(w, a, b, cc);
        h0[j] = a; h1[j] = b; h2[j] = cc;
    }
    unsigned short* p = d.Wf + wfbase;
    size_t fo = ((size_t)cg * KS + ks) * 3;
    *(us8*)(p + (fo + 0) * 512 + lane * 8) = h0;
    *(us8*)(p + (fo + 1) * 512 + lane * 8) = h1;
    *(us8*)(p + (fo + 2) * 512 + lane * 8) = h2;
}

// ------------------------------- level GEMM ----------------------------------
struct GMat {
    const float* A0; const float* A1;      // A1 = h-segment (L1 only)
    const unsigned short* Wf; const float* Wraw;
    const float* pred; float* S;
    int act; int ksteps;                   // 32 (K=1024) or 64 (K=2048)
};
struct GDesc { GMat m[3]; };

// WG: 512 thr / 8 waves. Covers 64 rows x 64 cols of c-half AND h-half.
// wave w: wr=w&1 (row 32-block), wc=w>>1: half=wc>>1 (c/h), cb=wc&1 (32-col blk).
template<int WMODE>
__global__ __launch_bounds__(512) void gemm_level(GDesc d) {
    __shared__ unsigned short Al[3][64][72];   // A limbs, KT=64, pad->stride 144B
    __shared__ float Ep[2][64][68];            // epilogue exchange (c,h)

    const int bx  = blockIdx.x;
    const GMat md = d.m[bx >> 4];
    const int wgc = bx & 15;
    const int tid = threadIdx.x;
    const int w = tid >> 6, lane = tid & 63;
    const int wr = w & 1, wc = w >> 1;
    const int half = wc >> 1, cb = wc & 1;
    const int cgbase = half * 64 + wgc * 4 + cb * 2;
    const int l15 = lane & 15, lg = lane >> 4;
    const int koff = lg * 8;

    f32x4 acc0[2][2] = {}, acc1[2][2] = {}, acc2[2][2] = {};

    const int ntiles = md.ksteps >> 1;     // KT=64 = 2 ksteps
    for (int kt = 0; kt < ntiles; ++kt) {
        // ---- stage A limb tile [64][64] ----
        {
            const float* Asrc; int ko;
            if (kt < 16) { Asrc = md.A0; ko = kt * 64; }
            else         { Asrc = md.A1; ko = (kt - 16) * 64; }
            int r = tid >> 3, kq = (tid & 7) * 8;
            const float* s = Asrc + (size_t)r * NH + ko + kq;
            float4 v0 = *(const float4*)s;
            float4 v1 = *(const float4*)(s + 4);
            float f[8] = {v0.x, v0.y, v0.z, v0.w, v1.x, v1.y, v1.z, v1.w};
            us8 q0, q1, q2;
            #pragma unroll
            for (int j = 0; j < 8; ++j) {
                unsigned short a, b, c2;
                limbs3(f[j], a, b, c2);
                q0[j] = a; q1[j] = b; q2[j] = c2;
            }
            __syncthreads();               // prev tile fully consumed
            *(us8*)&Al[0][r][kq] = q0;
            *(us8*)&Al[1][r][kq] = q1;
            *(us8*)&Al[2][r][kq] = q2;
            __syncthreads();
        }
        #pragma unroll
        for (int kk = 0; kk < 2; ++kk) {
            const int ks = kt * 2 + kk;
            half8 wf[2][3];
            if constexpr (WMODE == 0) {
                #pragma unroll
                for (int n = 0; n < 2; ++n) {
                    size_t fo = ((size_t)(cgbase + n) * md.ksteps + ks) * 3;
                    #pragma unroll
                    for (int t = 0; t < 3; ++t)
                        wf[n][t] = *(const half8*)(md.Wf + (fo + t) * 512 + lane * 8);
                }
            } else {
                #pragma unroll
                for (int n = 0; n < 2; ++n) {
                    int c  = (cgbase + n) * 16 + l15;
                    int kb = ks * 32 + koff;
                    us8 q0, q1, q2;
                    #pragma unroll
                    for (int j = 0; j < 8; ++j) {
                        float wv = md.Wraw[(size_t)(kb + j) * 2048 + c];
                        unsigned short a, b, c2;
                        limbs3(wv, a, b, c2);
                        q0[j] = a; q1[j] = b; q2[j] = c2;
                    }
                    wf[n][0] = __builtin_bit_cast(half8, q0);
                    wf[n][1] = __builtin_bit_cast(half8, q1);
                    wf[n][2] = __builtin_bit_cast(half8, q2);
                }
            }
            #pragma unroll
            for (int m = 0; m < 2; ++m) {
                const int row = wr * 32 + m * 16 + l15;
                const int kc  = kk * 32 + koff;
                half8 a0 = *(const half8*)&Al[0][row][kc];
                half8 a1 = *(const half8*)&Al[1][row][kc];
                half8 a2 = *(const half8*)&Al[2][row][kc];
                #pragma unroll
                for (int n = 0; n < 2; ++n) {
                    acc0[m][n] = __builtin_amdgcn_mfma_f32_16x16x32_f16(a0, wf[n][0], acc0[m][n], 0, 0, 0);
                    acc1[m][n] = __builtin_amdgcn_mfma_f32_16x16x32_f16(a0, wf[n][1], acc1[m][n], 0, 0, 0);
                    acc1[m][n] = __builtin_amdgcn_mfma_f32_16x16x32_f16(a1, wf[n][0], acc1[m][n], 0, 0, 0);
                    acc2[m][n] = __builtin_amdgcn_mfma_f32_16x16x32_f16(a0, wf[n][2], acc2[m][n], 0, 0, 0);
                    acc2[m][n] = __builtin_amdgcn_mfma_f32_16x16x32_f16(a1, wf[n][1], acc2[m][n], 0, 0, 0);
                    acc2[m][n] = __builtin_amdgcn_mfma_f32_16x16x32_f16(a2, wf[n][0], acc2[m][n], 0, 0, 0);
                }
            }
        }
    }

    // ---- epilogue: recombine limb accs, exchange via LDS, fused combine ----
    #pragma unroll
    for (int m = 0; m < 2; ++m)
        #pragma unroll
        for (int n = 0; n < 2; ++n) {
            const int colw = cb * 32 + n * 16 + l15;
            #pragma unroll
            for (int reg = 0; reg < 4; ++reg) {
                int row = wr * 32 + m * 16 + lg * 4 + reg;
                float v = acc0[m][n][reg] +
                          (acc1[m][n][reg] + acc2[m][n][reg] * INV_SCALE) * INV_SCALE;
                Ep[half][row][colw] = v;
            }
        }
    __syncthreads();
    {
        int r = tid >> 3, c8 = (tid & 7) * 8;
        int colg = wgc * 64 + c8;
        float4 cv0 = *(float4*)&Ep[0][r][c8];
        float4 cv1 = *(float4*)&Ep[0][r][c8 + 4];
        float4 hv0 = *(float4*)&Ep[1][r][c8];
        float4 hv1 = *(float4*)&Ep[1][r][c8 + 4];
        float4 p0 = *(const float4*)&md.pred[(size_t)r * NH + colg];
        float4 p1 = *(const float4*)&md.pred[(size_t)r * NH + colg + 4];
        const float cc[8] = {cv0.x, cv0.y, cv0.z, cv0.w, cv1.x, cv1.y, cv1.z, cv1.w};
        const float hh[8] = {hv0.x, hv0.y, hv0.z, hv0.w, hv1.x, hv1.y, hv1.z, hv1.w};
        const float pp[8] = {p0.x, p0.y, p0.z, p0.w, p1.x, p1.y, p1.z, p1.w};
        float o[8];
        #pragma unroll
        for (int j = 0; j < 8; ++j)
            o[j] = pp[j] + sigf(cc[j]) * (actf(md.act, hh[j]) - pp[j]);
        *(float4*)&md.S[(size_t)r * NH + colg]     = make_float4(o[0], o[1], o[2], o[3]);
        *(float4*)&md.S[(size_t)r * NH + colg + 4] = make_float4(o[4], o[5], o[6], o[7]);
    }
}

// --------------------- level 5: two GEMMs from s5 + mean ---------------------
struct G5 {
    const float* s5;
    const unsigned short* Wf6; const unsigned short* Wf8;
    const float* W6raw; const float* W8raw;
    const float* s1; const float* s2; const float* s3; const float* s4; const float* s7;
    float* out;
};

// WG covers 32 cols x quarters {c6,h6,c8,h8}. wave: wr=w&1, q=w>>1.
template<int WMODE>
__global__ __launch_bounds__(512) void gemm_l5(G5 d) {
    __shared__ unsigned short Al[3][64][72];
    __shared__ float Ep[4][64][36];

    const int wgc = blockIdx.x;            // 0..31
    const int tid = threadIdx.x;
    const int w = tid >> 6, lane = tid & 63;
    const int wr = w & 1, q = w >> 1;
    const unsigned short* Wf = (q < 2) ? d.Wf6 : d.Wf8;
    const float* Wraw        = (q < 2) ? d.W6raw : d.W8raw;
    const int half = q & 1;
    const int cgbase = half * 64 + wgc * 2;
    const int l15 = lane & 15, lg = lane >> 4;
    const int koff = lg * 8;

    f32x4 acc0[2][2] = {}, acc1[2][2] = {}, acc2[2][2] = {};

    for (int kt = 0; kt < 16; ++kt) {
        {
            int r = tid >> 3, kq = (tid & 7) * 8;
            const float* s = d.s5 + (size_t)r * NH + kt * 64 + kq;
            float4 v0 = *(const float4*)s;
            float4 v1 = *(const float4*)(s + 4);
            float f[8] = {v0.x, v0.y, v0.z, v0.w, v1.x, v1.y, v1.z, v1.w};
            us8 q0, q1, q2;
            #pragma unroll
            for (int j = 0; j < 8; ++j) {
                unsigned short a, b, c2;
                limbs3(f[j], a, b, c2);
                q0[j] = a; q1[j] = b; q2[j] = c2;
            }
            __syncthreads();
            *(us8*)&Al[0][r][kq] = q0;
            *(us8*)&Al[1][r][kq] = q1;
            *(us8*)&Al[2][r][kq] = q2;
            __syncthreads();
        }
        #pragma unroll
        for (int kk = 0; kk < 2; ++kk) {
            const int ks = kt * 2 + kk;
            half8 wf[2][3];
            if constexpr (WMODE == 0) {
                #pragma unroll
                for (int n = 0; n < 2; ++n) {
                    size_t fo = ((size_t)(cgbase + n) * 32 + ks) * 3;
                    #pragma unroll
                    for (int t = 0; t < 3; ++t)
                        wf[n][t] = *(const half8*)(Wf + (fo + t) * 512 + lane * 8);
                }
            } else {
                #pragma unroll
                for (int n = 0; n < 2; ++n) {
                    int c  = (cgbase + n) * 16 + l15;
                    int kb = ks * 32 + koff;
                    us8 q0, q1, q2;
                    #pragma unroll
                    for (int j = 0; j < 8; ++j) {
                        float wv = Wraw[(size_t)(kb + j) * 2048 + c];
                        unsigned short a, b, c2;
                        limbs3(wv, a, b, c2);
                        q0[j] = a; q1[j] = b; q2[j] = c2;
                    }
                    wf[n][0] = __builtin_bit_cast(half8, q0);
                    wf[n][1] = __builtin_bit_cast(half8, q1);
                    wf[n][2] = __builtin_bit_cast(half8, q2);
                }
            }
            #pragma unroll
            for (int m = 0; m < 2; ++m) {
                const int row = wr * 32 + m * 16 + l15;
                const int kc  = kk * 32 + koff;
                half8 a0 = *(const half8*)&Al[0][row][kc];
                half8 a1 = *(const half8*)&Al[1][row][kc];
                half8 a2 = *(const half8*)&Al[2][row][kc];
                #pragma unroll
                for (int n = 0; n < 2; ++n) {
                    acc0[m][n] = __builtin_amdgcn_mfma_f32_16x16x32_f16(a0, wf[n][0], acc0[m][n], 0, 0, 0);
                    acc1[m][n] = __builtin_amdgcn_mfma_f32_16x16x32_f16(a0, wf[n][1], acc1[m][n], 0, 0, 0);
                    acc1[m][n] = __builtin_amdgcn_mfma_f32_16x16x32_f16(a1, wf[n][0], acc1[m][n], 0, 0, 0);
                    acc2[m][n] = __builtin_amdgcn_mfma_f32_16x16x32_f16(a0, wf[n][2], acc2[m][n], 0, 0, 0);
                    acc2[m][n] = __builtin_amdgcn_mfma_f32_16x16x32_f16(a1, wf[n][1], acc2[m][n], 0, 0, 0);
                    acc2[m][n] = __builtin_amdgcn_mfma_f32_16x16x32_f16(a2, wf[n][0], acc2[m][n], 0, 0, 0);
                }
            }
        }
    }

    #pragma unroll
    for (int m = 0; m < 2; ++m)
        #pragma unroll
        for (int n = 0; n < 2; ++n) {
            const int colw = n * 16 + l15;
            #pragma unroll
            for (int reg = 0; reg < 4; ++reg) {
                int row = wr * 32 + m * 16 + lg * 4 + reg;
                float v = acc0[m][n][reg] +
                          (acc1[m][n][reg] + acc2[m][n][reg] * INV_SCALE) * INV_SCALE;
                Ep[q][row][colw] = v;
            }
        }
    __syncthreads();
    {
        int r = tid >> 3, c4 = (tid & 7) * 4;
        int colg = wgc * 32 + c4;
        size_t o = (size_t)r * NH + colg;
        float4 c6 = *(float4*)&Ep[0][r][c4];
        float4 h6 = *(float4*)&Ep[1][r][c4];
        float4 c8 = *(float4*)&Ep[2][r][c4];
        float4 h8 = *(float4*)&Ep[3][r][c4];
        float4 s5v = *(const float4*)&d.s5[o];
        float4 s1v = *(const float4*)&d.s1[o];
        float4 s2v = *(const float4*)&d.s2[o];
        float4 s3v = *(const float4*)&d.s3[o];
        float4 s4v = *(const float4*)&d.s4[o];
        float4 s7v = *(const float4*)&d.s7[o];
        float oo[4];
        const float c6a[4] = {c6.x, c6.y, c6.z, c6.w}, h6a[4] = {h6.x, h6.y, h6.z, h6.w};
        const float c8a[4] = {c8.x, c8.y, c8.z, c8.w}, h8a[4] = {h8.x, h8.y, h8.z, h8.w};
        const float s5a[4] = {s5v.x, s5v.y, s5v.z, s5v.w};
        const float sums[4] = {s1v.x + s2v.x + s3v.x + s4v.x + s7v.x,
                               s1v.y + s2v.y + s3v.y + s4v.y + s7v.y,
                               s1v.z + s2v.z + s3v.z + s4v.z + s7v.z,
                               s1v.w + s2v.w + s3v.w + s4v.w + s7v.w};
        #pragma unroll
        for (int j = 0; j < 4; ++j) {
            float s6 = s5a[j] + sigf(c6a[j]) * (sigf(h6a[j]) - s5a[j]);
            float s8 = s5a[j] + sigf(c8a[j]) * (fmaxf(h8a[j], 0.f) - s5a[j]);
            oo[j] = 0.125f * (sums[j] + s5a[j] + s6 + s8);
        }
        *(float4*)&d.out[o] = make_float4(oo[0], oo[1], oo[2], oo[3]);
    }
}

// ---------------------------------- host -------------------------------------
extern "C" void kernel_launch(void* const* d_in, const int* in_sizes, int n_in,
                              void* d_out, int out_size, void* d_ws, size_t ws_size,
                              hipStream_t stream) {
    (void)in_sizes; (void)n_in; (void)out_size;
    const float* inputs = (const float*)d_in[0];   // [256][64][1024]
    const float* hidden = (const float*)d_in[1];   // [1][64][1024]
    const float* W0     = (const float*)d_in[2];   // [2048][2048]
    const float* Ws     = (const float*)d_in[3];   // [8][1024][2048]
    float* out = (float*)d_out;

    const size_t need = WF_TOTAL_US * 2 + 7ull * 65536 * 4;
    const bool pre = ws_size >= need;

    unsigned short* Wf = (unsigned short*)d_ws;
    float* states = pre ? (float*)((char*)d_ws + WF_TOTAL_US * 2) : (float*)d_ws;
    float* s0 = states + 0 * 65536;
    float* s1 = states + 1 * 65536;
    float* s2 = states + 2 * 65536;
    float* s3 = states + 3 * 65536;
    float* s4 = states + 4 * 65536;
    float* s5 = states + 5 * 65536;
    float* s7 = states + 6 * 65536;

    const unsigned short* Wf0 = Wf;
    const unsigned short* Wfs[8];
    for (int i = 0; i < 8; ++i) Wfs[i] = Wf + WF_W0_US + (size_t)i * WF_WS_US;

    if (pre) {
        PreDesc pd{W0, Ws, Wf};
        preconv_kernel<<<10240, 256, 0, stream>>>(pd);
    }

#define LAUNCH_LVL(GRID, DESC) \
    do { if (pre) gemm_level<0><<<GRID, 512, 0, stream>>>(DESC); \
         else     gemm_level<1><<<GRID, 512, 0, stream>>>(DESC); } while (0)

    for (int t = 0; t < 256; ++t) {
        const float* xt = inputs + (size_t)t * 65536;
        const float* hp = t ? out + (size_t)(t - 1) * 65536 : hidden;

        GDesc d1{};
        d1.m[0] = {xt, hp, Wf0, W0, hp, s0, ACT_TANH, 64};
        LAUNCH_LVL(16, d1);

        GDesc d2{};
        d2.m[0] = {s0, s0, Wfs[0], Ws + (size_t)0 * WSZ, s0, s1, ACT_SIGMOID, 32};
        LAUNCH_LVL(16, d2);

        GDesc d3{};
        d3.m[0] = {s1, s1, Wfs[1], Ws + (size_t)1 * WSZ, s1, s2, ACT_RELU, 32};
        d3.m[1] = {s1, s1, Wfs[2], Ws + (size_t)2 * WSZ, s1, s3, ACT_RELU, 32};
        d3.m[2] = {s1, s1, Wfs[3], Ws + (size_t)3 * WSZ, s1, s4, ACT_IDENT, 32};
        LAUNCH_LVL(48, d3);

        GDesc d4{};
        d4.m[0] = {s2, s2, Wfs[4], Ws + (size_t)4 * WSZ, s2, s5, ACT_TANH, 32};
        d4.m[1] = {s3, s3, Wfs[6], Ws + (size_t)6 * WSZ, s3, s7, ACT_TANH, 32};
        LAUNCH_LVL(32, d4);

        G5 d5{s5, Wfs[5], Wfs[7], Ws + (size_t)5 * WSZ, Ws + (size_t)7 * WSZ,
              s1, s2, s3, s4, s7, out + (size_t)t * 65536};
        if (pre) gemm_l5<0><<<32, 512, 0, stream>>>(d5);
        else     gemm_l5<1><<<32, 512, 0, stream>>>(d5);
    }
#undef LAUNCH_LVL
}

// Round 3
// 14043.169 us; speedup vs baseline: 3.8987x; 3.8987x over previous
//
#include <hip/hip_runtime.h>
#include <math.h>

// DARTS recurrent cell on MI355X — MFMA fp16 2-limb split GEMMs, weight-stream design.
// x = l0 + l1/2048 (limbs scaled into fp16 range); acc = a0w0 + (a0w1 + a1w0)/2048.
// Wave tile: 16 rows x (16 c-cols + paired 16 h-cols) -> combine is lane-local.
// WG = 4 waves K-split (K/4 each), LDS reduce at epilogue. 256 WGs per GEMM.
// Producer epilogues write fp16 limb planes so consumer k-loops do zero conversion.

typedef __attribute__((ext_vector_type(8))) _Float16 half8;
typedef __attribute__((ext_vector_type(4))) float f32x4;

#define NH 1024
#define SCALE 2048.f
#define INVS  (1.f / 2048.f)

#define ACT_SIGMOID 0
#define ACT_RELU    1
#define ACT_IDENT   2
#define ACT_TANH    3

__device__ __forceinline__ float sigf(float x) { return 1.f / (1.f + expf(-x)); }
__device__ __forceinline__ float actf(int a, float x) {
    if (a == ACT_SIGMOID) return sigf(x);
    if (a == ACT_RELU)    return x > 0.f ? x : 0.f;
    if (a == ACT_TANH)    return tanhf(x);
    return x;
}
__device__ __forceinline__ void limbs2(float x, _Float16& a0, _Float16& a1) {
    a0 = (_Float16)x;
    a1 = (_Float16)((x - (float)a0) * SCALE);
}

// ---------------- weight pre-swizzle: frag-pair (cg 0..127, ks) = 1024 ushorts
// layout: limb0[512] | limb1[512]; element = lane*8 + j, with
// col = cg*16 + (lane&15), k = ks*32 + (lane>>4)*8 + j.
struct Pre { const float* W0; const float* Ws; unsigned short* wf; };

__global__ __launch_bounds__(256) void preconv(Pre d) {
    int gid  = blockIdx.x * 4 + (threadIdx.x >> 6);
    int lane = threadIdx.x & 63;
    const float* W; unsigned short* dst; int nks, cg, ks;
    if (gid < 8192) {                       // W0: 128 cg x 64 ks
        W = d.W0; dst = d.wf; nks = 64; cg = gid >> 6; ks = gid & 63;
    } else {                                // Ws[m]: 128 cg x 32 ks
        int g = gid - 8192; int mm = g >> 12; int wi = g & 4095;
        W   = d.Ws + (size_t)mm * (1024 * 2048);
        dst = d.wf + 8388608ull + (size_t)mm * 4194304ull;
        nks = 32; cg = wi >> 5; ks = wi & 31;
    }
    int c  = cg * 16 + (lane & 15);
    int kb = ks * 32 + (lane >> 4) * 8;
    half8 h0, h1;
    #pragma unroll
    for (int j = 0; j < 8; ++j) {
        float wv = W[(size_t)(kb + j) * 2048 + c];
        _Float16 p, q; limbs2(wv, p, q);
        h0[j] = p; h1[j] = q;
    }
    unsigned short* o = dst + ((size_t)cg * nks + ks) * 1024 + lane * 8;
    *(half8*)o         = h0;
    *(half8*)(o + 512) = h1;
}

__global__ __launch_bounds__(256) void zero_buf(float4* p) {
    p[blockIdx.x * 256 + threadIdx.x] = make_float4(0.f, 0.f, 0.f, 0.f);
}

// ------------------------------- level GEMM ----------------------------------
struct Mat {
    const float* xraw;                 // L1 only: x source [64][1024] (k 0..1023)
    const _Float16* al0; const _Float16* al1;   // A limb planes [64][1024]
    const unsigned short* wf;          // fragment buffer (PRE)
    const float* wraw;                 // raw W [K][2048] (fallback)
    const float* pred;
    float* s;                          // fp32 state out [64][1024]
    _Float16* sl0; _Float16* sl1;      // limb planes out (null if unused)
    int act; int nks;                  // 64 (K=2048, L1) or 32
};
struct Lvl { Mat m[3]; };

template<int PRE>
__global__ __launch_bounds__(256) void gemm_lvl(Lvl d) {
    const int bx  = blockIdx.x;
    const Mat m   = d.m[bx >> 8];
    const int t8  = bx & 255;
    const int rt  = t8 >> 6, cg = t8 & 63;
    const int wave = threadIdx.x >> 6, lane = threadIdx.x & 63;
    const int l15 = lane & 15, lg = lane >> 4;
    const int row = rt * 16 + l15;
    const int nq  = m.nks >> 2;
    const int ks0 = wave * nq;

    f32x4 c0 = {}, c1 = {}, h0 = {}, h1 = {};

    for (int i = 0; i < nq; ++i) {
        const int ks = ks0 + i;
        half8 a0, a1;
        if (m.xraw && ks < 32) {       // uniform per wave
            const float* xp = m.xraw + (size_t)row * NH + ks * 32 + lg * 8;
            float4 v0 = *(const float4*)xp;
            float4 v1 = *(const float4*)(xp + 4);
            float f[8] = {v0.x, v0.y, v0.z, v0.w, v1.x, v1.y, v1.z, v1.w};
            #pragma unroll
            for (int j = 0; j < 8; ++j) {
                _Float16 p, q; limbs2(f[j], p, q);
                a0[j] = p; a1[j] = q;
            }
        } else {
            const int kk = m.xraw ? ks - 32 : ks;
            const size_t ao = (size_t)row * NH + kk * 32 + lg * 8;
            a0 = *(const half8*)(m.al0 + ao);
            a1 = *(const half8*)(m.al1 + ao);
        }
        half8 w0c, w1c, w0h, w1h;
        if (PRE) {
            const unsigned short* pc = m.wf + ((size_t)cg        * m.nks + ks) * 1024 + lane * 8;
            const unsigned short* ph = m.wf + ((size_t)(cg + 64) * m.nks + ks) * 1024 + lane * 8;
            w0c = *(const half8*)pc; w1c = *(const half8*)(pc + 512);
            w0h = *(const half8*)ph; w1h = *(const half8*)(ph + 512);
        } else {
            const int c  = cg * 16 + l15;
            const int kb = ks * 32 + lg * 8;
            #pragma unroll
            for (int j = 0; j < 8; ++j) {
                float wc = m.wraw[(size_t)(kb + j) * 2048 + c];
                float wh = m.wraw[(size_t)(kb + j) * 2048 + c + 1024];
                _Float16 p, q;
                limbs2(wc, p, q); w0c[j] = p; w1c[j] = q;
                limbs2(wh, p, q); w0h[j] = p; w1h[j] = q;
            }
        }
        c0 = __builtin_amdgcn_mfma_f32_16x16x32_f16(a0, w0c, c0, 0, 0, 0);
        c1 = __builtin_amdgcn_mfma_f32_16x16x32_f16(a0, w1c, c1, 0, 0, 0);
        c1 = __builtin_amdgcn_mfma_f32_16x16x32_f16(a1, w0c, c1, 0, 0, 0);
        h0 = __builtin_amdgcn_mfma_f32_16x16x32_f16(a0, w0h, h0, 0, 0, 0);
        h1 = __builtin_amdgcn_mfma_f32_16x16x32_f16(a0, w1h, h1, 0, 0, 0);
        h1 = __builtin_amdgcn_mfma_f32_16x16x32_f16(a1, w0h, h1, 0, 0, 0);
    }

    __shared__ float red[4][2][256];
    #pragma unroll
    for (int r = 0; r < 4; ++r) {
        red[wave][0][lane * 4 + r] = c0[r] + c1[r] * INVS;
        red[wave][1][lane * 4 + r] = h0[r] + h1[r] * INVS;
    }
    __syncthreads();
    {
        const int t = threadIdx.x;
        const int rowf = t >> 4, col = t & 15;
        const int idx = ((rowf >> 2) << 6) + col * 4 + (rowf & 3);
        float cs = red[0][0][idx] + red[1][0][idx] + red[2][0][idx] + red[3][0][idx];
        float hs = red[0][1][idx] + red[1][1][idx] + red[2][1][idx] + red[3][1][idx];
        const size_t o = (size_t)(rt * 16 + rowf) * NH + cg * 16 + col;
        float p = m.pred[o];
        float v = p + sigf(cs) * (actf(m.act, hs) - p);
        m.s[o] = v;
        if (m.sl0) { _Float16 u0, u1; limbs2(v, u0, u1); m.sl0[o] = u0; m.sl1[o] = u1; }
    }
}

// --------------------- level 5: s6,s8 from s5 + fused mean --------------------
struct L5d {
    const _Float16* al0; const _Float16* al1;           // s5 limbs
    const unsigned short* wf6; const unsigned short* wf8;
    const float* w6raw; const float* w8raw;
    const float* s1; const float* s2; const float* s3; const float* s4;
    const float* s5; const float* s7;
    float* out; _Float16* hl0; _Float16* hl1;
};

template<int PRE>
__global__ __launch_bounds__(256) void gemm_l5(L5d d) {
    const int t8  = blockIdx.x;
    const int rt  = t8 >> 6, cg = t8 & 63;
    const int wave = threadIdx.x >> 6, lane = threadIdx.x & 63;
    const int l15 = lane & 15, lg = lane >> 4;
    const int row = rt * 16 + l15;
    const int ks0 = wave * 8;

    f32x4 c60 = {}, c61 = {}, h60 = {}, h61 = {};
    f32x4 c80 = {}, c81 = {}, h80 = {}, h81 = {};

    for (int i = 0; i < 8; ++i) {
        const int ks = ks0 + i;
        const size_t ao = (size_t)row * NH + ks * 32 + lg * 8;
        half8 a0 = *(const half8*)(d.al0 + ao);
        half8 a1 = *(const half8*)(d.al1 + ao);
        half8 w0c6, w1c6, w0h6, w1h6, w0c8, w1c8, w0h8, w1h8;
        if (PRE) {
            const unsigned short* pc6 = d.wf6 + ((size_t)cg        * 32 + ks) * 1024 + lane * 8;
            const unsigned short* ph6 = d.wf6 + ((size_t)(cg + 64) * 32 + ks) * 1024 + lane * 8;
            const unsigned short* pc8 = d.wf8 + ((size_t)cg        * 32 + ks) * 1024 + lane * 8;
            const unsigned short* ph8 = d.wf8 + ((size_t)(cg + 64) * 32 + ks) * 1024 + lane * 8;
            w0c6 = *(const half8*)pc6; w1c6 = *(const half8*)(pc6 + 512);
            w0h6 = *(const half8*)ph6; w1h6 = *(const half8*)(ph6 + 512);
            w0c8 = *(const half8*)pc8; w1c8 = *(const half8*)(pc8 + 512);
            w0h8 = *(const half8*)ph8; w1h8 = *(const half8*)(ph8 + 512);
        } else {
            const int c  = cg * 16 + l15;
            const int kb = ks * 32 + lg * 8;
            #pragma unroll
            for (int j = 0; j < 8; ++j) {
                _Float16 p, q;
                limbs2(d.w6raw[(size_t)(kb + j) * 2048 + c],        p, q); w0c6[j] = p; w1c6[j] = q;
                limbs2(d.w6raw[(size_t)(kb + j) * 2048 + c + 1024], p, q); w0h6[j] = p; w1h6[j] = q;
                limbs2(d.w8raw[(size_t)(kb + j) * 2048 + c],        p, q); w0c8[j] = p; w1c8[j] = q;
                limbs2(d.w8raw[(size_t)(kb + j) * 2048 + c + 1024], p, q); w0h8[j] = p; w1h8[j] = q;
            }
        }
        c60 = __builtin_amdgcn_mfma_f32_16x16x32_f16(a0, w0c6, c60, 0, 0, 0);
        c61 = __builtin_amdgcn_mfma_f32_16x16x32_f16(a0, w1c6, c61, 0, 0, 0);
        c61 = __builtin_amdgcn_mfma_f32_16x16x32_f16(a1, w0c6, c61, 0, 0, 0);
        h60 = __builtin_amdgcn_mfma_f32_16x16x32_f16(a0, w0h6, h60, 0, 0, 0);
        h61 = __builtin_amdgcn_mfma_f32_16x16x32_f16(a0, w1h6, h61, 0, 0, 0);
        h61 = __builtin_amdgcn_mfma_f32_16x16x32_f16(a1, w0h6, h61, 0, 0, 0);
        c80 = __builtin_amdgcn_mfma_f32_16x16x32_f16(a0, w0c8, c80, 0, 0, 0);
        c81 = __builtin_amdgcn_mfma_f32_16x16x32_f16(a0, w1c8, c81, 0, 0, 0);
        c81 = __builtin_amdgcn_mfma_f32_16x16x32_f16(a1, w0c8, c81, 0, 0, 0);
        h80 = __builtin_amdgcn_mfma_f32_16x16x32_f16(a0, w0h8, h80, 0, 0, 0);
        h81 = __builtin_amdgcn_mfma_f32_16x16x32_f16(a0, w1h8, h81, 0, 0, 0);
        h81 = __builtin_amdgcn_mfma_f32_16x16x32_f16(a1, w0h8, h81, 0, 0, 0);
    }

    __shared__ float red[4][4][256];
    #pragma unroll
    for (int r = 0; r < 4; ++r) {
        red[wave][0][lane * 4 + r] = c60[r] + c61[r] * INVS;
        red[wave][1][lane * 4 + r] = h60[r] + h61[r] * INVS;
        red[wave][2][lane * 4 + r] = c80[r] + c81[r] * INVS;
        red[wave][3][lane * 4 + r] = h80[r] + h81[r] * INVS;
    }
    __syncthreads();
    {
        const int t = threadIdx.x;
        const int rowf = t >> 4, col = t & 15;
        const int idx = ((rowf >> 2) << 6) + col * 4 + (rowf & 3);
        float c6 = red[0][0][idx] + red[1][0][idx] + red[2][0][idx] + red[3][0][idx];
        float h6 = red[0][1][idx] + red[1][1][idx] + red[2][1][idx] + red[3][1][idx];
        float c8 = red[0][2][idx] + red[1][2][idx] + red[2][2][idx] + red[3][2][idx];
        float h8 = red[0][3][idx] + red[1][3][idx] + red[2][3][idx] + red[3][3][idx];
        const size_t o = (size_t)(rt * 16 + rowf) * NH + cg * 16 + col;
        float s5v = d.s5[o];
        float s6  = s5v + sigf(c6) * (sigf(h6) - s5v);
        float s8  = s5v + sigf(c8) * (fmaxf(h8, 0.f) - s5v);
        float v = 0.125f * (d.s1[o] + d.s2[o] + d.s3[o] + d.s4[o] + s5v + s6 + d.s7[o] + s8);
        d.out[o] = v;
        _Float16 u0, u1; limbs2(v, u0, u1);
        d.hl0[o] = u0; d.hl1[o] = u1;
    }
}

// ---------------------------------- host -------------------------------------
extern "C" void kernel_launch(void* const* d_in, const int* in_sizes, int n_in,
                              void* d_out, int out_size, void* d_ws, size_t ws_size,
                              hipStream_t stream) {
    (void)in_sizes; (void)n_in; (void)out_size;
    const float* inputs = (const float*)d_in[0];   // [256][64][1024]
    const float* hidden = (const float*)d_in[1];   // [1][64][1024]
    const float* W0     = (const float*)d_in[2];   // [2048][2048]
    const float* Ws     = (const float*)d_in[3];   // [8][1024][2048]
    float* out = (float*)d_out;

    // ws layout: 7 fp32 state planes | 6 limb-plane pairs (h,s0,s1,s2,s3,s5) | Wf
    char* base = (char*)d_ws;
    float* S[7];                                   // s0,s1,s2,s3,s4,s5,s7
    for (int i = 0; i < 7; ++i) S[i] = (float*)(base + (size_t)i * 262144);
    _Float16* L0[6]; _Float16* L1[6];              // h,s0,s1,s2,s3,s5
    char* lb = base + 7ull * 262144;
    for (int i = 0; i < 6; ++i) {
        L0[i] = (_Float16*)(lb + (size_t)i * 262144);
        L1[i] = (_Float16*)(lb + (size_t)i * 262144 + 131072);
    }
    unsigned short* wf = (unsigned short*)(base + 13ull * 262144);
    const size_t NEED = 13ull * 262144 + 83886080ull;   // 87.3 MB
    const bool pre = ws_size >= NEED;

    unsigned short* wf0 = wf;
    unsigned short* wfs[8];
    for (int i = 0; i < 8; ++i) wfs[i] = wf + 8388608ull + (size_t)i * 4194304ull;

    if (pre) preconv<<<10240, 256, 0, stream>>>(Pre{W0, Ws, wf});
    zero_buf<<<64, 256, 0, stream>>>((float4*)L0[0]);   // h limb planes (t=0: h=0)

    _Float16 *hl0 = L0[0], *hl1 = L1[0];
    _Float16 *s0l0 = L0[1], *s0l1 = L1[1], *s1l0 = L0[2], *s1l1 = L1[2];
    _Float16 *s2l0 = L0[3], *s2l1 = L1[3], *s3l0 = L0[4], *s3l1 = L1[4];
    _Float16 *s5l0 = L0[5], *s5l1 = L1[5];

#define GL(G, D) do { if (pre) gemm_lvl<1><<<G, 256, 0, stream>>>(D); \
                      else     gemm_lvl<0><<<G, 256, 0, stream>>>(D); } while (0)

    for (int t = 0; t < 256; ++t) {
        const float* xt = inputs + (size_t)t * 65536;
        const float* hp = t ? out + (size_t)(t - 1) * 65536 : hidden;

        Lvl d1{}; d1.m[0] = {xt, hl0, hl1, wf0, W0, hp, S[0], s0l0, s0l1, ACT_TANH, 64};
        GL(256, d1);

        Lvl d2{}; d2.m[0] = {nullptr, s0l0, s0l1, wfs[0], Ws, S[0], S[1], s1l0, s1l1, ACT_SIGMOID, 32};
        GL(256, d2);

        Lvl d3{};
        d3.m[0] = {nullptr, s1l0, s1l1, wfs[1], Ws + 1ull * 2097152, S[1], S[2], s2l0, s2l1, ACT_RELU, 32};
        d3.m[1] = {nullptr, s1l0, s1l1, wfs[2], Ws + 2ull * 2097152, S[1], S[3], s3l0, s3l1, ACT_RELU, 32};
        d3.m[2] = {nullptr, s1l0, s1l1, wfs[3], Ws + 3ull * 2097152, S[1], S[4], nullptr, nullptr, ACT_IDENT, 32};
        GL(768, d3);

        Lvl d4{};
        d4.m[0] = {nullptr, s2l0, s2l1, wfs[4], Ws + 4ull * 2097152, S[2], S[5], s5l0, s5l1, ACT_TANH, 32};
        d4.m[1] = {nullptr, s3l0, s3l1, wfs[6], Ws + 6ull * 2097152, S[3], S[6], nullptr, nullptr, ACT_TANH, 32};
        GL(512, d4);

        L5d d5{s5l0, s5l1, wfs[5], wfs[7],
               Ws + 5ull * 2097152, Ws + 7ull * 2097152,
               S[1], S[2], S[3], S[4], S[5], S[6],
               out + (size_t)t * 65536, hl0, hl1};
        if (pre) gemm_l5<1><<<256, 256, 0, stream>>>(d5);
        else     gemm_l5<0><<<256, 256, 0, stream>>>(d5);
    }
#undef GL
}